// Round 2
// baseline (270.671 us; speedup 1.0000x reference)
//
#include <hip/hip_runtime.h>

// SCVC: out[n,o,i,j] = sum_{c,d} x[n,c,i] y[n,d,j] Cr[o,c,d]
//                      + a[n,o,i] + b[n,o,j] + bias[o]
// a = dilated conv (k=2, pad=1, dil=2) of channel-tiled x, W_A folded over the
// tile-repeat (a[n,o,i] = sum_c x[c,i-1]*WA'[c,0] + x[c,i+1]*WA'[c,1]);
// b likewise for y / W_B.  N=32, IN1=IN2=4, OUT=128, DX=DY=128. All float32.

__global__ __launch_bounds__(256) void scvc_kernel(
    const float* __restrict__ x,     // [32,4,128]
    const float* __restrict__ y,     // [32,4,128]
    const float* __restrict__ C,     // [128,16]
    const float* __restrict__ WA,    // [128,16,2]
    const float* __restrict__ WB,    // [128,16,2]
    const float* __restrict__ bias,  // [128]
    float* __restrict__ out)         // [32,128,128,128]
{
    const int n   = blockIdx.x >> 7;    // 0..31
    const int o   = blockIdx.x & 127;   // 0..127
    const int tid = threadIdx.x;

    __shared__ float csh[16];       // Cr[c*4+d]
    __shared__ float wash[8];       // folded W_A: [c*2+k]
    __shared__ float wbsh[8];       // folded W_B: [c*2+k]
    __shared__ float t4[128][4];    // t4[i][d] = sum_c x[c,i]*Cr[c,d]
    __shared__ float arow[128];
    __shared__ float bcol[128];

    const float* xb = x + n * 512;
    const float* yb = y + n * 512;

    // ---- phase 0: fold weights into LDS (32 threads) ----
    if (tid < 16) {
        csh[tid] = C[o * 16 + tid];
    } else if (tid < 24) {
        const int idx = tid - 16;           // c*2 + k
        const int c = idx >> 1, k = idx & 1;
        float s = 0.f;
        #pragma unroll
        for (int r = 0; r < 4; ++r) s += WA[o * 32 + (4 * r + c) * 2 + k];
        wash[idx] = s;
    } else if (tid < 32) {
        const int idx = tid - 24;
        const int c = idx >> 1, k = idx & 1;
        float s = 0.f;
        #pragma unroll
        for (int r = 0; r < 4; ++r) s += WB[o * 32 + (4 * r + c) * 2 + k];
        wbsh[idx] = s;
    }
    __syncthreads();

    // ---- phase 1: per-row t4 & arow (threads 0..127), per-col bcol (128..255) ----
    if (tid < 128) {
        const int i = tid;
        float xv[4], xm[4], xp[4];
        #pragma unroll
        for (int c = 0; c < 4; ++c) {
            xv[c] = xb[c * 128 + i];
            xm[c] = (i > 0)   ? xb[c * 128 + i - 1] : 0.f;  // conv tap t-1
            xp[c] = (i < 127) ? xb[c * 128 + i + 1] : 0.f;  // conv tap t+1
        }
        #pragma unroll
        for (int d = 0; d < 4; ++d) {
            float s = 0.f;
            #pragma unroll
            for (int c = 0; c < 4; ++c) s += xv[c] * csh[c * 4 + d];
            t4[i][d] = s;
        }
        float a = 0.f;
        #pragma unroll
        for (int c = 0; c < 4; ++c)
            a += xm[c] * wash[c * 2] + xp[c] * wash[c * 2 + 1];
        arow[i] = a;
    } else {
        const int j = tid - 128;
        float b = 0.f;
        #pragma unroll
        for (int c = 0; c < 4; ++c) {
            float ym = (j > 0)   ? yb[c * 128 + j - 1] : 0.f;
            float yp = (j < 127) ? yb[c * 128 + j + 1] : 0.f;
            b += ym * wbsh[c * 2] + yp * wbsh[c * 2 + 1];
        }
        bcol[j] = b;
    }
    __syncthreads();

    // ---- phase 2: each thread owns 8 fixed columns, sweeps 8 rows ----
    const int j0 = (tid & 15) * 8;
    float yr[4][8];
    #pragma unroll
    for (int d = 0; d < 4; ++d) {
        const float4 v0 = *(const float4*)(yb + d * 128 + j0);
        const float4 v1 = *(const float4*)(yb + d * 128 + j0 + 4);
        yr[d][0] = v0.x; yr[d][1] = v0.y; yr[d][2] = v0.z; yr[d][3] = v0.w;
        yr[d][4] = v1.x; yr[d][5] = v1.y; yr[d][6] = v1.z; yr[d][7] = v1.w;
    }
    const float bv = bias[o];
    float bj[8];
    #pragma unroll
    for (int jj = 0; jj < 8; ++jj) bj[jj] = bcol[j0 + jj] + bv;

    float* op = out + ((long)blockIdx.x << 14) + j0;  // [n,o] tile base
    const int irow = tid >> 4;
    #pragma unroll
    for (int it = 0; it < 8; ++it) {
        const int i = irow + it * 16;
        const float4 t = *(const float4*)(&t4[i][0]);  // ds_read_b128, 16-lane broadcast
        const float ai = arow[i];
        float v[8];
        #pragma unroll
        for (int jj = 0; jj < 8; ++jj) {
            v[jj] = t.x * yr[0][jj] + t.y * yr[1][jj] +
                    t.z * yr[2][jj] + t.w * yr[3][jj] + ai + bj[jj];
        }
        float4 r0 = make_float4(v[0], v[1], v[2], v[3]);
        float4 r1 = make_float4(v[4], v[5], v[6], v[7]);
        *(float4*)(op + i * 128)     = r0;  // coalesced 16B stores
        *(float4*)(op + i * 128 + 4) = r1;
    }
}

extern "C" void kernel_launch(void* const* d_in, const int* in_sizes, int n_in,
                              void* d_out, int out_size, void* d_ws, size_t ws_size,
                              hipStream_t stream) {
    const float* x    = (const float*)d_in[0];
    const float* y    = (const float*)d_in[1];
    const float* C    = (const float*)d_in[2];
    const float* WA   = (const float*)d_in[3];
    const float* WB   = (const float*)d_in[4];
    const float* bias = (const float*)d_in[5];
    float* out = (float*)d_out;

    scvc_kernel<<<32 * 128, 256, 0, stream>>>(x, y, C, WA, WB, bias, out);
}

// Round 3
// 265.153 us; speedup vs baseline: 1.0208x; 1.0208x over previous
//
#include <hip/hip_runtime.h>

// SCVC: out[n,o,i,j] = sum_{c,d} x[n,c,i] y[n,d,j] Cr[o,c,d]
//                      + a[n,o,i] + b[n,o,j] + bias[o]
// a = dilated conv (k=2, pad=1, dil=2) of channel-tiled x, W_A folded over the
// tile-repeat; b likewise for y / W_B.
// N=32, IN1=IN2=4, OUT=128, DX=DY=128. All float32.
// Store-bandwidth-bound: 256 MB out vs ~400 KB in. Phase 2 is laid out so each
// wave store instruction covers 2 full adjacent rows (1 KB, 100% dense).

__global__ __launch_bounds__(256) void scvc_kernel(
    const float* __restrict__ x,     // [32,4,128]
    const float* __restrict__ y,     // [32,4,128]
    const float* __restrict__ C,     // [128,16]
    const float* __restrict__ WA,    // [128,16,2]
    const float* __restrict__ WB,    // [128,16,2]
    const float* __restrict__ bias,  // [128]
    float* __restrict__ out)         // [32,128,128,128]
{
    const int n   = blockIdx.x >> 7;    // 0..31
    const int o   = blockIdx.x & 127;   // 0..127
    const int tid = threadIdx.x;

    __shared__ float csh[16];       // Cr[c*4+d]
    __shared__ float wash[8];       // folded W_A: [c*2+k]
    __shared__ float wbsh[8];       // folded W_B: [c*2+k]
    __shared__ float t4[128][4];    // t4[i][d] = sum_c x[c,i]*Cr[c,d]
    __shared__ float arow[128];
    __shared__ float bcol[128];     // includes bias

    const float* xb = x + n * 512;
    const float* yb = y + n * 512;

    // ---- phase 0: fold weights into LDS (32 threads) ----
    if (tid < 16) {
        csh[tid] = C[o * 16 + tid];
    } else if (tid < 24) {
        const int idx = tid - 16;           // c*2 + k
        const int c = idx >> 1, k = idx & 1;
        float s = 0.f;
        #pragma unroll
        for (int r = 0; r < 4; ++r) s += WA[o * 32 + (4 * r + c) * 2 + k];
        wash[idx] = s;
    } else if (tid < 32) {
        const int idx = tid - 24;
        const int c = idx >> 1, k = idx & 1;
        float s = 0.f;
        #pragma unroll
        for (int r = 0; r < 4; ++r) s += WB[o * 32 + (4 * r + c) * 2 + k];
        wbsh[idx] = s;
    }
    __syncthreads();

    // ---- phase 1: per-row t4 & arow (threads 0..127), per-col bcol (128..255) ----
    if (tid < 128) {
        const int i = tid;
        float xv[4], xm[4], xp[4];
        #pragma unroll
        for (int c = 0; c < 4; ++c) {
            xv[c] = xb[c * 128 + i];
            xm[c] = (i > 0)   ? xb[c * 128 + i - 1] : 0.f;  // conv tap t-1
            xp[c] = (i < 127) ? xb[c * 128 + i + 1] : 0.f;  // conv tap t+1
        }
        #pragma unroll
        for (int d = 0; d < 4; ++d) {
            float s = 0.f;
            #pragma unroll
            for (int c = 0; c < 4; ++c) s += xv[c] * csh[c * 4 + d];
            t4[i][d] = s;
        }
        float a = 0.f;
        #pragma unroll
        for (int c = 0; c < 4; ++c)
            a += xm[c] * wash[c * 2] + xp[c] * wash[c * 2 + 1];
        arow[i] = a;
    } else {
        const int j = tid - 128;
        float b = bias[o];
        #pragma unroll
        for (int c = 0; c < 4; ++c) {
            float ym = (j > 0)   ? yb[c * 128 + j - 1] : 0.f;
            float yp = (j < 127) ? yb[c * 128 + j + 1] : 0.f;
            b += ym * wbsh[c * 2] + yp * wbsh[c * 2 + 1];
        }
        bcol[j] = b;
    }
    __syncthreads();

    // ---- phase 2: thread owns 4 consecutive cols; 32 threads cover a row.
    // Wave = 2 adjacent rows per store instr -> fully dense 1 KB stores.
    const int col4 = (tid & 31) * 4;   // 0,4,...,124
    const int rgrp = tid >> 5;         // 0..7

    float yr[4][4];
    #pragma unroll
    for (int d = 0; d < 4; ++d) {
        const float4 v = *(const float4*)(yb + d * 128 + col4);
        yr[d][0] = v.x; yr[d][1] = v.y; yr[d][2] = v.z; yr[d][3] = v.w;
    }
    float bj[4];
    #pragma unroll
    for (int jj = 0; jj < 4; ++jj) bj[jj] = bcol[col4 + jj];

    float* op = out + ((long)blockIdx.x << 14) + col4;  // [n,o] tile base
    #pragma unroll
    for (int it = 0; it < 16; ++it) {
        const int i = rgrp + it * 8;
        const float4 t = *(const float4*)(&t4[i][0]);   // broadcast ds_read_b128
        const float ai = arow[i];
        float4 r;
        r.x = t.x * yr[0][0] + t.y * yr[1][0] + t.z * yr[2][0] + t.w * yr[3][0] + (ai + bj[0]);
        r.y = t.x * yr[0][1] + t.y * yr[1][1] + t.z * yr[2][1] + t.w * yr[3][1] + (ai + bj[1]);
        r.z = t.x * yr[0][2] + t.y * yr[1][2] + t.z * yr[2][2] + t.w * yr[3][2] + (ai + bj[2]);
        r.w = t.x * yr[0][3] + t.y * yr[1][3] + t.z * yr[2][3] + t.w * yr[3][3] + (ai + bj[3]);
        *(float4*)(op + i * 128) = r;                   // dense coalesced store
    }
}

extern "C" void kernel_launch(void* const* d_in, const int* in_sizes, int n_in,
                              void* d_out, int out_size, void* d_ws, size_t ws_size,
                              hipStream_t stream) {
    const float* x    = (const float*)d_in[0];
    const float* y    = (const float*)d_in[1];
    const float* C    = (const float*)d_in[2];
    const float* WA   = (const float*)d_in[3];
    const float* WB   = (const float*)d_in[4];
    const float* bias = (const float*)d_in[5];
    float* out = (float*)d_out;

    scvc_kernel<<<32 * 128, 256, 0, stream>>>(x, y, C, WA, WB, bias, out);
}